// Round 11
// baseline (228.749 us; speedup 1.0000x reference)
//
#include <hip/hip_runtime.h>
#include <cstdint>

typedef __bf16 bf16;
typedef __bf16 bf16x8 __attribute__((ext_vector_type(8)));
typedef float floatx4 __attribute__((ext_vector_type(4)));

#define MFMA32(a, b, c) __builtin_amdgcn_mfma_f32_16x16x32_bf16((a), (b), (c), 0, 0, 0)

__device__ inline bf16x8 cvt8(const float* p) {
    float4 u = *(const float4*)p;
    float4 v = *(const float4*)(p + 4);
    bf16x8 r;
    r[0] = (bf16)u.x; r[1] = (bf16)u.y; r[2] = (bf16)u.z; r[3] = (bf16)u.w;
    r[4] = (bf16)v.x; r[5] = (bf16)v.y; r[6] = (bf16)v.z; r[7] = (bf16)v.w;
    return r;
}

// ---------------------------------------------------------------------------
// Kernel 1: merged prep. z<4: transpose+convert one 512x512 weight matrix.
// z>=4: X fp32 -> bf16 chunk (8 z-slices x 256 blocks).
// ---------------------------------------------------------------------------
__global__ __launch_bounds__(256) void k_prep(
    const float* __restrict__ w0, const float* __restrict__ w1,
    const float* __restrict__ w2, const float* __restrict__ w3,
    const float* __restrict__ X,
    bf16* __restrict__ o0, bf16* __restrict__ o1,
    bf16* __restrict__ o2, bf16* __restrict__ o3,
    bf16* __restrict__ Xb)
{
    __shared__ float t[32][33];
    const int z = blockIdx.z;
    if (z >= 4) {
        const int idx = (z - 4) * 256 + blockIdx.y * 16 + blockIdx.x;
        const size_t e = ((size_t)idx * 256 + threadIdx.x) * 8;
        *(bf16x8*)(Xb + e) = cvt8(X + e);
        return;
    }
    const float* in;
    bf16* out;
    switch (z) {
        case 0: in = w0; out = o0; break;
        case 1: in = w1; out = o1; break;
        case 2: in = w2; out = o2; break;
        default: in = w3; out = o3; break;
    }
    const int tx = threadIdx.x & 31;
    const int ty = threadIdx.x >> 5;
    const int r0 = blockIdx.y * 32;
    const int c0 = blockIdx.x * 32;
    #pragma unroll
    for (int i = 0; i < 32; i += 8)
        t[ty + i][tx] = in[(size_t)(r0 + ty + i) * 512 + c0 + tx];
    __syncthreads();
    #pragma unroll
    for (int i = 0; i < 32; i += 8)
        out[(size_t)(c0 + ty + i) * 512 + r0 + tx] = (bf16)t[tx][ty + i];
}

// ---------------------------------------------------------------------------
// Kernel 2: QKV GEMM (128x128, BK=32, dbuf LDS) + per-wave LDS-transpose
// epilogue. V is written KEY-PERMUTED within each 32-key group: key
// l=16tm+4quad+r goes to position 32(tm>>1)+8quad+4(tm&1)+r, so attention's
// in-lane P^T (keys {4q..4q+3} of tile0 + {16+4q..} of tile1 per lane)
// matches the MFMA32 B-fragment k=8*quad+j against V A-fragments read as
// single b128s. Staging/copies are order-transparent.
// ---------------------------------------------------------------------------
__global__ __launch_bounds__(256) void k_qkv(
    const bf16* __restrict__ Xb, const bf16* __restrict__ Wcat,
    const float* __restrict__ bq, const float* __restrict__ bk, const float* __restrict__ bv,
    bf16* __restrict__ Qs, bf16* __restrict__ Ks, bf16* __restrict__ Vt)
{
    __shared__ __align__(16) unsigned char smem[36864];
    uint4* Al = (uint4*)smem;              // [2][512]
    uint4* Bl = (uint4*)(smem + 16384);    // [2][512]

    const int tid  = threadIdx.x;
    const int w    = tid >> 6;
    const int lane = tid & 63;
    const int col  = lane & 15;
    const int quad = lane >> 4;
    const int m0 = blockIdx.x * 128;
    const int n0 = blockIdx.y * 128;

    const bf16* gA0 = Xb   + (size_t)(m0 + (tid >> 2)) * 512 + (tid & 3) * 8;
    const bf16* gA1 = gA0 + 64 * 512;
    const bf16* gB0 = Wcat + (size_t)(n0 + (tid >> 2)) * 512 + (tid & 3) * 8;
    const bf16* gB1 = gB0 + 64 * 512;

    const floatx4 zf = {0.f, 0.f, 0.f, 0.f};
    floatx4 acc[4][4];
    #pragma unroll
    for (int a = 0; a < 4; ++a)
        #pragma unroll
        for (int b = 0; b < 4; ++b) acc[a][b] = zf;

    Al[tid]       = *(const uint4*)gA0;
    Al[tid + 256] = *(const uint4*)gA1;
    Bl[tid]       = *(const uint4*)gB0;
    Bl[tid + 256] = *(const uint4*)gB1;
    __syncthreads();

    const int mb = (w & 1) * 64;
    const int nb = (w >> 1) * 64;

    int buf = 0;
    for (int kk = 0; kk < 16; ++kk) {
        const int kn = ((kk + 1) & 15) * 32;
        const uint4 pa0 = *(const uint4*)(gA0 + kn);
        const uint4 pa1 = *(const uint4*)(gA1 + kn);
        const uint4 pb0 = *(const uint4*)(gB0 + kn);
        const uint4 pb1 = *(const uint4*)(gB1 + kn);

        const uint4* A4 = Al + buf * 512;
        const uint4* B4 = Bl + buf * 512;
        bf16x8 af[4], bfr[4];
        #pragma unroll
        for (int t = 0; t < 4; ++t) {
            union { uint4 u; bf16x8 v; } ca, cb;
            ca.u = A4[(mb + 16 * t + col) * 4 + quad];
            cb.u = B4[(nb + 16 * t + col) * 4 + quad];
            af[t] = ca.v;
            bfr[t] = cb.v;
        }
        #pragma unroll
        for (int tm = 0; tm < 4; ++tm)
            #pragma unroll
            for (int tn = 0; tn < 4; ++tn)
                acc[tm][tn] = MFMA32(af[tm], bfr[tn], acc[tm][tn]);

        const int nbuf = buf ^ 1;
        Al[nbuf * 512 + tid]       = pa0;
        Al[nbuf * 512 + tid + 256] = pa1;
        Bl[nbuf * 512 + tid]       = pb0;
        Bl[nbuf * 512 + tid + 256] = pb1;
        __syncthreads();
        buf = nbuf;
    }

    bf16* ep = (bf16*)smem + (size_t)w * 64 * 72;

    const int which = blockIdx.y >> 2;
    const int nbase = (blockIdx.y & 3) * 128 + nb;
    const int h  = nbase >> 6;
    const int mw = m0 + mb;
    const int b  = mw >> 12;
    const int s0 = mw & 4095;
    const float qsc = 0.125f * 1.44269504088896f;

    if (which == 2) {
        #pragma unroll
        for (int tn = 0; tn < 4; ++tn) {
            const int d = 16 * tn + col;
            const float bb = bv[nbase + d];
            #pragma unroll
            for (int tm = 0; tm < 4; ++tm) {
                union { bf16 e[4]; uint2 u; } pk;
                #pragma unroll
                for (int r = 0; r < 4; ++r) pk.e[r] = (bf16)(acc[tm][tn][r] + bb);
                // key-permuted position within 32-group (see header comment)
                const int sl = 32 * (tm >> 1) + 8 * quad + 4 * (tm & 1);
                *(uint2*)(ep + d * 72 + sl) = pk.u;
            }
        }
    } else {
        const float* bias = (which == 0) ? bq : bk;
        const float sc = (which == 0) ? qsc : 1.0f;
        #pragma unroll
        for (int tn = 0; tn < 4; ++tn) {
            const int d = 16 * tn + col;
            const float bb = bias[nbase + d];
            #pragma unroll
            for (int tm = 0; tm < 4; ++tm)
                #pragma unroll
                for (int r = 0; r < 4; ++r)
                    ep[(16 * tm + 4 * quad + r) * 72 + d] = (bf16)((acc[tm][tn][r] + bb) * sc);
        }
    }

    asm volatile("" ::: "memory");

    const int rl = lane >> 3;
    const int ch = lane & 7;
    bf16* gbase;
    size_t rowstride;
    if (which == 2) {
        gbase = Vt + (((size_t)b * 8 + h) * 64) * 4096 + s0;
        rowstride = 4096;
    } else {
        bf16* P = (which == 0) ? Qs : Ks;
        gbase = P + (((size_t)b * 8 + h) * 4096 + s0) * 64;
        rowstride = 64;
    }
    #pragma unroll
    for (int it = 0; it < 8; ++it) {
        const int row = it * 8 + rl;
        const uint4 v = *(const uint4*)(ep + row * 72 + ch * 8);
        *(uint4*)(gbase + (size_t)row * rowstride + ch * 8) = v;
    }
}

// ---------------------------------------------------------------------------
// Kernel 3: attention, 64 q/wave (256 q/block), 256 blocks (1/CU).
// S^T = K*Q^T (MFMA32); exp -> in-lane 8-key pack (key-permuted Vt makes it
// the exact MFMA32 B-fragment) -> O^T += V^T*P^T all on MFMA32, K=32.
// K tile: 64B-row XOR-swizzled LDS. V tile: 64 d-rows x 80B stride.
// Double-buffered, one barrier/iter, streaming softmax with raw v_exp.
// ---------------------------------------------------------------------------
__global__ __launch_bounds__(256) void k_attn(
    const bf16* __restrict__ Qs, const bf16* __restrict__ Ks, const bf16* __restrict__ Vt,
    bf16* __restrict__ att)
{
    __shared__ uint4 Klds[2][256];
    __shared__ __align__(16) unsigned char Vlds[2][64 * 80];

    const int tid  = threadIdx.x;
    const int w    = tid >> 6;
    const int lane = tid & 63;
    const int col  = lane & 15;
    const int quad = lane >> 4;
    const int i    = blockIdx.x;
    const int bh   = ((i & 7) << 1) | ((i >> 3) & 1);   // 2 heads per XCD
    const int q0   = (i >> 4) * 256 + w * 64;

    const bf16* Qb = Qs + (size_t)bh * 262144;
    const bf16* Kb = Ks + (size_t)bh * 262144;
    const bf16* Vb = Vt + (size_t)bh * 262144;

    // staging geometry
    const int rK  = tid >> 3;
    const int lcK = (tid & 7) ^ (rK & 7);
    const bf16* gK = Kb + (size_t)rK * 64 + lcK * 8;
    const int dV = tid >> 2;                 // d-row 0..63
    const int cV = tid & 3;                  // 16B chunk (8 keys)
    const bf16* gV = Vb + (size_t)dV * 4096 + cV * 8;
    const int vOff = dV * 80 + cV * 16;      // LDS byte offset

    // Q fragments: 4 q-sets x 2 dim-halves
    bf16x8 aq[4][2];
    #pragma unroll
    for (int s = 0; s < 4; ++s)
        #pragma unroll
        for (int c = 0; c < 2; ++c)
            aq[s][c] = *(const bf16x8*)(Qb + (size_t)(q0 + 16 * s + col) * 64 + 32 * c + quad * 8);

    const floatx4 zf = {0.f, 0.f, 0.f, 0.f};
    floatx4 o[4][4];                 // O^T: lane holds q=col, d=16dt+4quad+r
    float lsum[4] = {0.f, 0.f, 0.f, 0.f};
    #pragma unroll
    for (int s = 0; s < 4; ++s)
        #pragma unroll
        for (int dt = 0; dt < 4; ++dt) o[s][dt] = zf;

    Klds[0][tid] = *(const uint4*)gK;
    *(uint4*)(Vlds[0] + vOff) = *(const uint4*)gV;
    __syncthreads();

    int buf = 0;
    for (int kt = 0; kt < 4096; kt += 32) {
        const int kn = (kt + 32) & 4095;
        const uint4 kreg = *(const uint4*)(gK + (size_t)kn * 64);
        const uint4 vreg = *(const uint4*)(gV + kn);

        const uint4* Kl = Klds[buf];
        const unsigned char* Vlb = Vlds[buf];

        bf16x8 kf[2][2];
        #pragma unroll
        for (int t = 0; t < 2; ++t)
            #pragma unroll
            for (int c = 0; c < 2; ++c) {
                union { uint4 u; bf16x8 v; } cv;
                cv.u = Kl[(16 * t + col) * 8 + ((quad + 4 * c) ^ (col & 7))];
                kf[t][c] = cv.v;
            }
        // V^T A-fragments: single b128 per d-tile (key-permuted layout)
        bf16x8 vf[4];
        #pragma unroll
        for (int dt = 0; dt < 4; ++dt) {
            union { uint4 u; bf16x8 v; } cv;
            cv.u = *(const uint4*)(Vlb + (16 * dt + col) * 80 + quad * 16);
            vf[dt] = cv.v;
        }

        #pragma unroll
        for (int s = 0; s < 4; ++s) {
            union { bf16 e[8]; bf16x8 v; } pk;
            #pragma unroll
            for (int t = 0; t < 2; ++t) {
                floatx4 sc = MFMA32(kf[t][1], aq[s][1], MFMA32(kf[t][0], aq[s][0], zf));
                const float p0 = __builtin_amdgcn_exp2f(sc[0]);
                const float p1 = __builtin_amdgcn_exp2f(sc[1]);
                const float p2 = __builtin_amdgcn_exp2f(sc[2]);
                const float p3 = __builtin_amdgcn_exp2f(sc[3]);
                lsum[s] += (p0 + p1) + (p2 + p3);
                pk.e[4 * t + 0] = (bf16)p0;
                pk.e[4 * t + 1] = (bf16)p1;
                pk.e[4 * t + 2] = (bf16)p2;
                pk.e[4 * t + 3] = (bf16)p3;
            }
            #pragma unroll
            for (int dt = 0; dt < 4; ++dt)
                o[s][dt] = MFMA32(vf[dt], pk.v, o[s][dt]);
        }

        Klds[buf ^ 1][tid] = kreg;
        *(uint4*)(Vlds[buf ^ 1] + vOff) = vreg;
        __syncthreads();
        buf ^= 1;
    }

    float inv[4];
    #pragma unroll
    for (int s = 0; s < 4; ++s) {
        float v = lsum[s];
        v += __shfl_xor(v, 16, 64);
        v += __shfl_xor(v, 32, 64);
        inv[s] = 1.0f / v;
    }

    const int b = bh >> 3;
    const int h = bh & 7;
    #pragma unroll
    for (int s = 0; s < 4; ++s)
        #pragma unroll
        for (int dt = 0; dt < 4; ++dt) {
            union { bf16 e[4]; uint2 u; } pk;
            #pragma unroll
            for (int r = 0; r < 4; ++r) pk.e[r] = (bf16)(o[s][dt][r] * inv[s]);
            const size_t row = (size_t)b * 4096 + q0 + 16 * s + col;
            *(uint2*)(att + row * 512 + h * 64 + 16 * dt + 4 * quad) = pk.u;
        }
}

// ---------------------------------------------------------------------------
// Kernel 4: output projection GEMM, 128x64 tiles (grid 64x8 = 512 blocks,
// 2/CU). Wave tile 64x32 (acc 4x2). out fp32 = att @ Wto^T + bo.
// ---------------------------------------------------------------------------
__global__ __launch_bounds__(256) void k_oproj(
    const bf16* __restrict__ att, const bf16* __restrict__ Wto,
    const float* __restrict__ bo, float* __restrict__ out)
{
    __shared__ uint4 Al[2][512];
    __shared__ uint4 Bl[2][256];

    const int tid  = threadIdx.x;
    const int w    = tid >> 6;
    const int lane = tid & 63;
    const int col  = lane & 15;
    const int quad = lane >> 4;
    const int m0 = blockIdx.x * 128;
    const int n0 = blockIdx.y * 64;

    const bf16* gA0 = att + (size_t)(m0 + (tid >> 2)) * 512 + (tid & 3) * 8;
    const bf16* gA1 = gA0 + 64 * 512;
    const bf16* gB0 = Wto + (size_t)(n0 + (tid >> 2)) * 512 + (tid & 3) * 8;

    const floatx4 zf = {0.f, 0.f, 0.f, 0.f};
    floatx4 acc[4][2];
    #pragma unroll
    for (int a = 0; a < 4; ++a)
        #pragma unroll
        for (int b = 0; b < 2; ++b) acc[a][b] = zf;

    Al[0][tid]       = *(const uint4*)gA0;
    Al[0][tid + 256] = *(const uint4*)gA1;
    Bl[0][tid]       = *(const uint4*)gB0;
    __syncthreads();

    const int mb = (w & 1) * 64;
    const int nb = (w >> 1) * 32;

    int buf = 0;
    for (int kk = 0; kk < 16; ++kk) {
        const int kn = ((kk + 1) & 15) * 32;
        const uint4 pa0 = *(const uint4*)(gA0 + kn);
        const uint4 pa1 = *(const uint4*)(gA1 + kn);
        const uint4 pb0 = *(const uint4*)(gB0 + kn);

        const uint4* A4 = Al[buf];
        const uint4* B4 = Bl[buf];
        bf16x8 af[4], bfr[2];
        #pragma unroll
        for (int t = 0; t < 4; ++t) {
            union { uint4 u; bf16x8 v; } ca;
            ca.u = A4[(mb + 16 * t + col) * 4 + quad];
            af[t] = ca.v;
        }
        #pragma unroll
        for (int t = 0; t < 2; ++t) {
            union { uint4 u; bf16x8 v; } cb;
            cb.u = B4[(nb + 16 * t + col) * 4 + quad];
            bfr[t] = cb.v;
        }
        #pragma unroll
        for (int tm = 0; tm < 4; ++tm)
            #pragma unroll
            for (int tn = 0; tn < 2; ++tn)
                acc[tm][tn] = MFMA32(af[tm], bfr[tn], acc[tm][tn]);

        Al[buf ^ 1][tid]       = pa0;
        Al[buf ^ 1][tid + 256] = pa1;
        Bl[buf ^ 1][tid]       = pb0;
        __syncthreads();
        buf ^= 1;
    }

    #pragma unroll
    for (int tn = 0; tn < 2; ++tn) {
        const int n = n0 + nb + 16 * tn + col;
        const float bb = bo[n];
        #pragma unroll
        for (int tm = 0; tm < 4; ++tm)
            #pragma unroll
            for (int r = 0; r < 4; ++r) {
                const int m = m0 + mb + 16 * tm + quad * 4 + r;
                out[(size_t)m * 512 + n] = acc[tm][tn][r] + bb;
            }
    }
}

// ---------------------------------------------------------------------------
extern "C" void kernel_launch(void* const* d_in, const int* in_sizes, int n_in,
                              void* d_out, int out_size, void* d_ws, size_t ws_size,
                              hipStream_t stream)
{
    const float* X  = (const float*)d_in[0];
    const float* Wq = (const float*)d_in[1];
    const float* bq = (const float*)d_in[2];
    const float* Wk = (const float*)d_in[3];
    const float* bk = (const float*)d_in[4];
    const float* Wv = (const float*)d_in[5];
    const float* bv = (const float*)d_in[6];
    const float* Wo = (const float*)d_in[7];
    const float* bo = (const float*)d_in[8];

    // workspace (bf16 elements): Wcat(3) + Wto + Q + K + Vt + att = 34.1 MB
    bf16* Wtq = (bf16*)d_ws;
    bf16* Wtk = Wtq + 512 * 512;
    bf16* Wtv = Wtk + 512 * 512;
    bf16* Wto = Wtv + 512 * 512;
    bf16* Qs  = Wto + 512 * 512;               // [16][4096][64]
    bf16* Ks  = Qs + (size_t)16 * 4096 * 64;   // [16][4096][64]
    bf16* Vt  = Ks + (size_t)16 * 4096 * 64;   // [16][64][4096] key-permuted
    bf16* att = Vt + (size_t)16 * 4096 * 64;   // [8192][512]

    bf16* Xb  = (bf16*)d_out;                  // scratch; consumed by k_qkv

    k_prep<<<dim3(16, 16, 12), 256, 0, stream>>>(Wq, Wk, Wv, Wo, X,
                                                 Wtq, Wtk, Wtv, Wto, Xb);
    k_qkv<<<dim3(64, 12), 256, 0, stream>>>(Xb, Wtq, bq, bk, bv, Qs, Ks, Vt);
    k_attn<<<256, 256, 0, stream>>>(Qs, Ks, Vt, att);
    k_oproj<<<dim3(64, 8), 256, 0, stream>>>(att, Wto, bo, (float*)d_out);
}